// Round 25
// baseline (113.978 us; speedup 1.0000x reference)
//
#include <hip/hip_runtime.h>

#define NUM_K 64
#define CDIM 32
#define HW 16384          // 128*128
#define NPTS 1048576      // 64*128*128
#define NELEMD 33554432.0 // 64*32*128*128

typedef float v2f __attribute__((ext_vector_type(2)));

// numpy pairwise sum of squares, n=32 contiguous: 8 accumulators + fixed tree.
__device__ __forceinline__ float np_sumsq32(const float* v) {
#pragma clang fp contract(off)
    float r[8];
    #pragma unroll
    for (int j = 0; j < 8; ++j) {
        float p0 = v[j] * v[j];
        float p1 = v[j + 8] * v[j + 8];
        float p2 = v[j + 16] * v[j + 16];
        float p3 = v[j + 24] * v[j + 24];
        r[j] = ((p0 + p1) + p2) + p3;
    }
    return ((r[0] + r[1]) + (r[2] + r[3])) + ((r[4] + r[5]) + (r[6] + r[7]));
}

// Prep: B[k] = np.sum(emb*emb,axis=1) (numpy fp32 order) and embT[c][k]
// (transposed codebook, contiguous in k) -> global scratch.
__global__ void vq_prep(const float* __restrict__ emb, float* __restrict__ Bg,
                        float* __restrict__ embT) {
#pragma clang fp contract(off)
    int k = threadIdx.x;
    if (k < NUM_K) {
        float e[CDIM];
        #pragma unroll
        for (int c = 0; c < CDIM; ++c) e[c] = emb[k * CDIM + c];
        Bg[k] = np_sumsq32(e);
        #pragma unroll
        for (int c = 0; c < CDIM; ++c) embT[c * NUM_K + k] = e[c];
    }
}

// R10 with ONE change: the dot-product loop reads codebook rows from LDS
// (sET, uniform address -> HW broadcast, conflict-free) instead of via
// s_load from global. Mechanism under test: SMEM returns are OUT-OF-ORDER
// (lgkmcnt must drain to 0 before each c-step's FMAs -> the stuck ~35%
// VALUBusy of R9/R10/R18/R19); DS returns are IN-ORDER, enabling the
// compiler's fine-grained lgkmcnt(N) partial waits and deep pipelining.
__global__ __launch_bounds__(256) void vq_main(const float* __restrict__ x,
                                               const float* __restrict__ embT,
                                               const float* __restrict__ Bg,
                                               float* __restrict__ outq,
                                               double* __restrict__ ws) {
#pragma clang fp contract(off)
    __shared__ float sET[CDIM][NUM_K];  // codebook rows (embT layout) + gather table
    __shared__ float sRed[4];

    const int t = threadIdx.x;
    #pragma unroll
    for (int i = t; i < NUM_K * CDIM; i += 256)
        ((float*)sET)[i] = embT[i];     // coalesced read, conflict-free write
    __syncthreads();

    const int p = blockIdx.x * 256 + t;
    const int b = p >> 14;
    const size_t base = (size_t)b * (CDIM * HW) + (p & (HW - 1));
    const float* xp = x + base;

    v2f acc2[CDIM];                     // acc2[q] = {C_{2q}, C_{2q+1}}
    #pragma unroll
    for (int q = 0; q < CDIM; ++q) acc2[q] = (v2f){0.f, 0.f};
    float r[8];                         // numpy pairwise-tree partials for A

    float cur[8], nxt[8];
    #pragma unroll
    for (int j = 0; j < 8; ++j)
        cur[j] = xp[(size_t)j * HW];    // prologue: group 0 loads (vmcnt stream)

    #pragma unroll
    for (int g = 0; g < 4; ++g) {
        if (g < 3) {                    // issue next group's loads FIRST
            #pragma unroll
            for (int j = 0; j < 8; ++j)
                nxt[j] = xp[(size_t)((g + 1) * 8 + j) * HW];
        }
        #pragma unroll
        for (int j = 0; j < 8; ++j) {
            const int c = g * 8 + j;
            const float xc = cur[j];
            const float pp = xc * xc;               // rounds individually
            // r_j = ((p_j + p_{j+8}) + p_{j+16}) + p_{j+24}  == numpy tree
            if (g == 0) r[j] = pp; else r[j] = r[j] + pp;
            const v2f xx = (v2f){xc, xc};
            // LDS row, uniform addr -> broadcast ds_read (in-order returns)
            const v2f* __restrict__ e2 = (const v2f*)(&sET[c][0]);
            #pragma unroll
            for (int q = 0; q < CDIM; ++q)
                acc2[q] = __builtin_elementwise_fma(xx, e2[q], acc2[q]); // per-elem fma
        }
        if (g < 3) {
            #pragma unroll
            for (int j = 0; j < 8; ++j) cur[j] = nxt[j];   // register rotate
        }
    }
    const float A = ((r[0] + r[1]) + (r[2] + r[3])) + ((r[4] + r[5]) + (r[6] + r[7]));

    // d_k = fp32( fp32(A + B_k) - 2*C_k ) == fmaf(-2, C_k, A+B_k) bitwise.
    // Ascending k, strict <  => first-min (np.argmin). Each C_k saw the exact
    // ascending-c fp32 fma chain of all passing rounds.
    float best = 3.4028235e38f;
    int bi = 0;
    #pragma unroll
    for (int q = 0; q < CDIM; ++q) {
        float d0 = fmaf(-2.f, acc2[q].x, A + Bg[2 * q]);
        float d1 = fmaf(-2.f, acc2[q].y, A + Bg[2 * q + 1]);
        if (d0 < best) { best = d0; bi = 2 * q; }
        if (d1 < best) { best = d1; bi = 2 * q + 1; }
    }

    // Winner gather + coalesced stores. Loss contribution == best (validated R9).
    float* op = outq + base;
    #pragma unroll
    for (int c = 0; c < CDIM; ++c)
        op[(size_t)c * HW] = sET[c][bi];   // bank=bi%32 gather: ~free

    float lsum = best;
    #pragma unroll
    for (int off = 32; off > 0; off >>= 1)
        lsum += __shfl_down(lsum, off, 64);
    const int wid = t >> 6;
    if ((t & 63) == 0) sRed[wid] = lsum;
    __syncthreads();
    if (t == 0) {
        double bs = (double)sRed[0] + (double)sRed[1] + (double)sRed[2] + (double)sRed[3];
        atomicAdd(ws, bs);
    }
}

__global__ void vq_finish(const double* __restrict__ ws, float* __restrict__ loss) {
    loss[0] = (float)(1.25 * ws[0] / NELEMD);
}

extern "C" void kernel_launch(void* const* d_in, const int* in_sizes, int n_in,
                              void* d_out, int out_size, void* d_ws, size_t ws_size,
                              hipStream_t stream) {
    const float* x = (const float*)d_in[0];
    const float* emb = (const float*)d_in[1];
    float* out = (float*)d_out;
    // ws layout: [0,8) double loss acc; [64,320) Bg[64]; [320,8512) embT[32][64]
    double* acc = (double*)d_ws;
    float* Bg = (float*)((char*)d_ws + 64);
    float* embT = (float*)((char*)d_ws + 320);

    hipMemsetAsync(d_ws, 0, sizeof(double), stream);
    vq_prep<<<1, 64, 0, stream>>>(emb, Bg, embT);
    vq_main<<<NPTS / 256, 256, 0, stream>>>(x, embT, Bg, out + 1, acc);
    vq_finish<<<1, 1, 0, stream>>>(acc, out);
}

// Round 26
// 85.485 us; speedup vs baseline: 1.3333x; 1.3333x over previous
//
#include <hip/hip_runtime.h>

#define NUM_K 64
#define CDIM 32
#define HW 16384          // 128*128
#define NPTS 1048576      // 64*128*128
#define NELEMD 33554432.0 // 64*32*128*128

typedef float v2f __attribute__((ext_vector_type(2)));

// numpy pairwise sum of squares, n=32 contiguous: 8 accumulators + fixed tree.
__device__ __forceinline__ float np_sumsq32(const float* v) {
#pragma clang fp contract(off)
    float r[8];
    #pragma unroll
    for (int j = 0; j < 8; ++j) {
        float p0 = v[j] * v[j];
        float p1 = v[j + 8] * v[j + 8];
        float p2 = v[j + 16] * v[j + 16];
        float p3 = v[j + 24] * v[j + 24];
        r[j] = ((p0 + p1) + p2) + p3;
    }
    return ((r[0] + r[1]) + (r[2] + r[3])) + ((r[4] + r[5]) + (r[6] + r[7]));
}

// Prep: B[k] = np.sum(emb*emb,axis=1) (numpy fp32 order) and embT[c][k]
// (transposed codebook, contiguous in k) -> global scratch.
__global__ void vq_prep(const float* __restrict__ emb, float* __restrict__ Bg,
                        float* __restrict__ embT) {
#pragma clang fp contract(off)
    int k = threadIdx.x;
    if (k < NUM_K) {
        float e[CDIM];
        #pragma unroll
        for (int c = 0; c < CDIM; ++c) e[c] = emb[k * CDIM + c];
        Bg[k] = np_sumsq32(e);
        #pragma unroll
        for (int c = 0; c < CDIM; ++c) embT[c * NUM_K + k] = e[c];
    }
}

// FINAL KERNEL — session's measured optimum (84.7-86.0us over 4 reproductions).
// Structure: loop-interchanged (c outer, k inner), register-resident x,
// s_load codebook rows (measured faster than LDS broadcast, R25), packed v2f
// fma, bit-exact numpy fp32 distance replication (pairwise-tree ||x||^2,
// ascending-c fma chain, fmaf(-2,acc,A+B_k), strict-< first-min argmin).
// All alternative structures measured worse:
//   k-outer serial chains (R3-R8: remat/AGPR-parking, +10-170%)
//   occupancy k-splits (R11/R12/R14: spill or +163%)
//   MFMA screen+refine (R15: +220%)
//   v2f point-pairs (R19: +9%), half-k waves (R18: +48%)
//   LDS-broadcast codebook feed (R25: +33%)
// Residual ~2x gap to the ~45us memory floor = per-c-step SMEM drain +
// dependent latency; both feed mechanisms measured, s_load wins.
__global__ __launch_bounds__(256) void vq_main(const float* __restrict__ x,
                                               const float* __restrict__ embT,
                                               const float* __restrict__ Bg,
                                               float* __restrict__ outq,
                                               double* __restrict__ ws) {
#pragma clang fp contract(off)
    __shared__ float sET[CDIM][NUM_K];  // gather table (same layout as embT)
    __shared__ float sRed[4];

    const int t = threadIdx.x;
    #pragma unroll
    for (int i = t; i < NUM_K * CDIM; i += 256)
        ((float*)sET)[i] = embT[i];     // coalesced read, conflict-free write
    __syncthreads();

    const int p = blockIdx.x * 256 + t;
    const int b = p >> 14;
    const size_t base = (size_t)b * (CDIM * HW) + (p & (HW - 1));
    const float* xp = x + base;

    v2f acc2[CDIM];                     // acc2[q] = {C_{2q}, C_{2q+1}}
    #pragma unroll
    for (int q = 0; q < CDIM; ++q) acc2[q] = (v2f){0.f, 0.f};
    float r[8];                         // numpy pairwise-tree partials for A

    float cur[8], nxt[8];
    #pragma unroll
    for (int j = 0; j < 8; ++j)
        cur[j] = xp[(size_t)j * HW];    // prologue: group 0 loads

    #pragma unroll
    for (int g = 0; g < 4; ++g) {
        if (g < 3) {                    // issue next group's loads FIRST
            #pragma unroll
            for (int j = 0; j < 8; ++j)
                nxt[j] = xp[(size_t)((g + 1) * 8 + j) * HW];
        }
        #pragma unroll
        for (int j = 0; j < 8; ++j) {
            const int c = g * 8 + j;
            const float xc = cur[j];
            const float pp = xc * xc;               // rounds individually
            // r_j = ((p_j + p_{j+8}) + p_{j+16}) + p_{j+24}  == numpy tree
            if (g == 0) r[j] = pp; else r[j] = r[j] + pp;
            const v2f xx = (v2f){xc, xc};
            const v2f* __restrict__ e2 = (const v2f*)(embT + c * NUM_K); // uniform row
            #pragma unroll
            for (int q = 0; q < CDIM; ++q)
                acc2[q] = __builtin_elementwise_fma(xx, e2[q], acc2[q]); // per-elem fma
        }
        if (g < 3) {
            #pragma unroll
            for (int j = 0; j < 8; ++j) cur[j] = nxt[j];   // register rotate
        }
    }
    const float A = ((r[0] + r[1]) + (r[2] + r[3])) + ((r[4] + r[5]) + (r[6] + r[7]));

    // d_k = fp32( fp32(A + B_k) - 2*C_k ) == fmaf(-2, C_k, A+B_k) bitwise.
    // Ascending k, strict <  => first-min (np.argmin).
    float best = 3.4028235e38f;
    int bi = 0;
    #pragma unroll
    for (int q = 0; q < CDIM; ++q) {
        float d0 = fmaf(-2.f, acc2[q].x, A + Bg[2 * q]);
        float d1 = fmaf(-2.f, acc2[q].y, A + Bg[2 * q + 1]);
        if (d0 < best) { best = d0; bi = 2 * q; }
        if (d1 < best) { best = d1; bi = 2 * q + 1; }
    }

    // Winner gather + coalesced stores. Loss contribution == best (validated R9).
    float* op = outq + base;
    #pragma unroll
    for (int c = 0; c < CDIM; ++c)
        op[(size_t)c * HW] = sET[c][bi];   // bank=bi%32 gather: ~free

    float lsum = best;
    #pragma unroll
    for (int off = 32; off > 0; off >>= 1)
        lsum += __shfl_down(lsum, off, 64);
    const int wid = t >> 6;
    if ((t & 63) == 0) sRed[wid] = lsum;
    __syncthreads();
    if (t == 0) {
        double bs = (double)sRed[0] + (double)sRed[1] + (double)sRed[2] + (double)sRed[3];
        atomicAdd(ws, bs);
    }
}

__global__ void vq_finish(const double* __restrict__ ws, float* __restrict__ loss) {
    loss[0] = (float)(1.25 * ws[0] / NELEMD);
}

extern "C" void kernel_launch(void* const* d_in, const int* in_sizes, int n_in,
                              void* d_out, int out_size, void* d_ws, size_t ws_size,
                              hipStream_t stream) {
    const float* x = (const float*)d_in[0];
    const float* emb = (const float*)d_in[1];
    float* out = (float*)d_out;
    // ws layout: [0,8) double loss acc; [64,320) Bg[64]; [320,8512) embT[32][64]
    double* acc = (double*)d_ws;
    float* Bg = (float*)((char*)d_ws + 64);
    float* embT = (float*)((char*)d_ws + 320);

    hipMemsetAsync(d_ws, 0, sizeof(double), stream);
    vq_prep<<<1, 64, 0, stream>>>(emb, Bg, embT);
    vq_main<<<NPTS / 256, 256, 0, stream>>>(x, embT, Bg, out + 1, acc);
    vq_finish<<<1, 1, 0, stream>>>(acc, out);
}